// Round 4
// baseline (9048.315 us; speedup 1.0000x reference)
//
#include <hip/hip_runtime.h>
#include <hip/hip_bf16.h>

typedef __attribute__((ext_vector_type(8))) short v8s;
typedef __attribute__((ext_vector_type(4))) float v4f;

constexpr int T_  = 512;
constexpr int Dd  = 128;
constexpr int RS  = 65536;    // fp32 row stride of enc/dec/out: T*D
constexpr int AST = 648;      // Abuf row stride in shorts (640 cols + 8 pad)
constexpr int ZST = 68;       // zbuf row stride in floats
constexpr int ZW_ = 16 * ZST; // per-wave zbuf floats
constexpr int CST = 260;      // c row stride in floats

// ws offsets (bytes)
constexpr size_t OFF_BP0  = 0;        // 384x1024 bf16 frag-linear [W0;U0]
constexpr size_t OFF_BP1  = 786432;   // 256x1024 bf16 (W1+U1)
constexpr size_t OFF_BPD  = 1310720;  // 256x1024 bf16 (dU + oW@dW)
constexpr size_t OFF_BD0  = 1835008;  // 384x1024 bf16 [dW;dU]
constexpr size_t OFF_BPO  = 2621440;  // 256x128 bf16 oW
constexpr size_t OFF_B0P  = 2686976;  // 1024 f32 eb0 packed by col'
constexpr size_t OFF_B1P  = 2691072;  // 1024 f32 eb1
constexpr size_t OFF_BD0P = 2695168;  // 1024 f32 db
constexpr size_t OFF_BDRP = 2699264;  // 1024 f32 db + ob@dW
constexpr size_t OFF_OBP  = 2703360;  // 128 f32 ob

__device__ __forceinline__ unsigned short f2b(float x) {
    __hip_bfloat16 h = __float2bfloat16(x);
    return *(unsigned short*)&h;
}

// ---------------- prep: repack fp32 weights into MFMA-frag-linear bf16 -----
// Frag layout for a KxN matrix, 16x16x32 tiles: frag (nt,kt), lane l, elem e
// holds B[k = kt*32 + (l>>4)*8 + e][col = nt*16 + (l&15)], linear index
// ((nt*KT + kt)*64 + l)*8 + e.  Gate-interleaved cols: col' = jj*4+g -> n = g*256+jj.
__global__ void __launch_bounds__(256) prep_kernel(
    const float* __restrict__ eW0, const float* __restrict__ eU0,
    const float* __restrict__ eb0,
    const float* __restrict__ eW1, const float* __restrict__ eU1,
    const float* __restrict__ eb1,
    const float* __restrict__ dW,  const float* __restrict__ dU,
    const float* __restrict__ db,
    const float* __restrict__ oW,  const float* __restrict__ ob,
    char* __restrict__ ws)
{
    const size_t gid = (size_t)blockIdx.x * 256 + threadIdx.x;

    if (gid < 393216) {                       // Bp0 = [eW0; eU0], KT=12
        const size_t fid = gid;
        const int e = fid & 7, l = (fid >> 3) & 63, r = fid >> 9;
        const int kt = r % 12, nt = r / 12;
        const int k = kt * 32 + (l >> 4) * 8 + e;
        const int col = nt * 16 + (l & 15);
        const int n = (col & 3) * 256 + (col >> 2);
        const float v = (k < 128) ? eW0[(size_t)k * 1024 + n]
                                  : eU0[(size_t)(k - 128) * 1024 + n];
        ((unsigned short*)(ws + OFF_BP0))[fid] = f2b(v);
    } else if (gid < 655360) {                // Bp1 = W1+U1, KT=8
        const size_t fid = gid - 393216;
        const int e = fid & 7, l = (fid >> 3) & 63, r = fid >> 9;
        const int kt = r & 7, nt = r >> 3;
        const int k = kt * 32 + (l >> 4) * 8 + e;
        const int col = nt * 16 + (l & 15);
        const int n = (col & 3) * 256 + (col >> 2);
        ((unsigned short*)(ws + OFF_BP1))[fid] =
            f2b(eW1[(size_t)k * 1024 + n] + eU1[(size_t)k * 1024 + n]);
    } else if (gid < 917504) {                // Bpd = dU + oW@dW, KT=8
        const size_t fid = gid - 655360;
        const int e = fid & 7, l = (fid >> 3) & 63, r = fid >> 9;
        const int kt = r & 7, nt = r >> 3;
        const int k = kt * 32 + (l >> 4) * 8 + e;
        const int col = nt * 16 + (l & 15);
        const int n = (col & 3) * 256 + (col >> 2);
        float s = dU[(size_t)k * 1024 + n];
        for (int d = 0; d < 128; ++d)
            s += oW[(size_t)k * 128 + d] * dW[(size_t)d * 1024 + n];
        ((unsigned short*)(ws + OFF_BPD))[fid] = f2b(s);
    } else if (gid < 1310720) {               // Bd0 = [dW; dU], KT=12
        const size_t fid = gid - 917504;
        const int e = fid & 7, l = (fid >> 3) & 63, r = fid >> 9;
        const int kt = r % 12, nt = r / 12;
        const int k = kt * 32 + (l >> 4) * 8 + e;
        const int col = nt * 16 + (l & 15);
        const int n = (col & 3) * 256 + (col >> 2);
        const float v = (k < 128) ? dW[(size_t)k * 1024 + n]
                                  : dU[(size_t)(k - 128) * 1024 + n];
        ((unsigned short*)(ws + OFF_BD0))[fid] = f2b(v);
    } else if (gid < 1343488) {               // BpO = oW (256x128), KT=8, natural cols
        const size_t fid = gid - 1310720;
        const int e = fid & 7, l = (fid >> 3) & 63, r = fid >> 9;
        const int kt = r & 7, nt = r >> 3;
        const int k = kt * 32 + (l >> 4) * 8 + e;
        const int dcol = nt * 16 + (l & 15);
        ((unsigned short*)(ws + OFF_BPO))[fid] = f2b(oW[(size_t)k * 128 + dcol]);
    } else if (gid < 1344512) {               // biases packed by col'
        const int col = (int)(gid - 1343488);
        const int n = (col & 3) * 256 + (col >> 2);
        ((float*)(ws + OFF_B0P))[col]  = eb0[n];
        ((float*)(ws + OFF_B1P))[col]  = eb1[n];
        ((float*)(ws + OFF_BD0P))[col] = db[n];
        float s = db[n];
        for (int d = 0; d < 128; ++d)
            s += ob[d] * dW[(size_t)d * 1024 + n];
        ((float*)(ws + OFF_BDRP))[col] = s;
    } else if (gid < 1344640) {               // obp
        const int d = (int)(gid - 1344512);
        ((float*)(ws + OFF_OBP))[d] = ob[d];
    }
}

// ---------------- main persistent row-parallel kernel ----------------------
// 32 blocks x 1024 threads (16 waves).  Block owns batch rows [m0, m0+16).
// Abuf (bf16, row stride AST): cols 0..127 = x_t, 128..383 = h-state (h2 enc /
// h_d dec), 384..639 = h1 (encoder intermediate).  c: fp32 LDS, never rounded.
// Batch rows are independent -> no inter-block communication at all.

__device__ __forceinline__ void z_mfma(const unsigned short* __restrict__ Asub,
                                       const char* __restrict__ Bp, int KT,
                                       int w, int l, float* __restrict__ zw)
{
    const int cn = l & 15, kg = l >> 4;
    const unsigned short* aptr = Asub + cn * AST + kg * 8;
    const v8s* bp = (const v8s*)Bp + (size_t)(w * 4) * KT * 64 + l;

    v4f acc0 = {0.f,0.f,0.f,0.f}, acc1 = acc0, acc2 = acc0, acc3 = acc0;
    #pragma unroll 4
    for (int kt = 0; kt < KT; ++kt) {
        const v8s a  = *(const v8s*)(aptr + kt * 32);
        const v8s b0 = bp[(0 * KT + kt) * 64];
        const v8s b1 = bp[(1 * KT + kt) * 64];
        const v8s b2 = bp[(2 * KT + kt) * 64];
        const v8s b3 = bp[(3 * KT + kt) * 64];
        acc0 = __builtin_amdgcn_mfma_f32_16x16x32_bf16(a, b0, acc0, 0, 0, 0);
        acc1 = __builtin_amdgcn_mfma_f32_16x16x32_bf16(a, b1, acc1, 0, 0, 0);
        acc2 = __builtin_amdgcn_mfma_f32_16x16x32_bf16(a, b2, acc2, 0, 0, 0);
        acc3 = __builtin_amdgcn_mfma_f32_16x16x32_bf16(a, b3, acc3, 0, 0, 0);
    }
    // C layout: row(M) = kg*4+reg, col(N-local) = g*16 + cn
    #pragma unroll
    for (int reg = 0; reg < 4; ++reg) {
        const int rr = (kg * 4 + reg) * ZST;
        zw[rr + 0 * 16 + cn] = acc0[reg];
        zw[rr + 1 * 16 + cn] = acc1[reg];
        zw[rr + 2 * 16 + cn] = acc2[reg];
        zw[rr + 3 * 16 + cn] = acc3[reg];
    }
}

__device__ __forceinline__ void lstm_epi(const float* __restrict__ zw,
                                         const float* __restrict__ bias, // pre-offset +w*64
                                         float* __restrict__ cb,
                                         unsigned short* __restrict__ hdst, // Abuf + col offset
                                         int w, int l)
{
    const int jjl = l & 15, kg = l >> 4;
    const float4 b4 = *(const float4*)(bias + jjl * 4);
    const int j = w * 16 + jjl;
    #pragma unroll
    for (int i = 0; i < 4; ++i) {
        const int r = kg + i * 4;
        const float4 z4 = *(const float4*)&zw[r * ZST + jjl * 4];
        const float zi = z4.x + b4.x, zf = z4.y + b4.y;
        const float zg = z4.z + b4.z, zo = z4.w + b4.w;
        const float ii = 1.f / (1.f + __expf(-zi));
        const float ff = 1.f / (1.f + __expf(-zf));
        const float gg = fmaxf(zg, 0.f);
        const float oo = 1.f / (1.f + __expf(-zo));
        const float c = ff * cb[r * CST + j] + ii * gg;
        cb[r * CST + j] = c;
        hdst[r * AST + j] = f2b(oo * fmaxf(c, 0.f));
    }
}

__global__ void __launch_bounds__(1024) lstm_main(
    const float* __restrict__ enc_in, const float* __restrict__ dec_in,
    const char* __restrict__ ws, float* __restrict__ out)
{
    __shared__ __align__(16) unsigned short Abuf[16 * AST];
    __shared__ __align__(16) float zbuf[16 * ZW_];
    __shared__ __align__(16) float cbuf[16 * CST];

    const int tid = threadIdx.x;
    const int w = tid >> 6, l = tid & 63;
    const int m0 = blockIdx.x * 16;
    float* zw = zbuf + w * ZW_;

    const char* Bp0 = ws + OFF_BP0;
    const char* Bp1 = ws + OFF_BP1;
    const char* Bpd = ws + OFF_BPD;
    const char* Bd0 = ws + OFF_BD0;
    const v8s*  BpO = (const v8s*)(ws + OFF_BPO);
    const float* b0p  = (const float*)(ws + OFF_B0P)  + w * 64;
    const float* b1p  = (const float*)(ws + OFF_B1P)  + w * 64;
    const float* bd0p = (const float*)(ws + OFF_BD0P) + w * 64;
    const float* bDrp = (const float*)(ws + OFF_BDRP) + w * 64;
    const float* obp  = (const float*)(ws + OFF_OBP);

    // init: h-state cols 128..383 = 0, c = 0
    for (int idx = tid; idx < 16 * 128; idx += 1024) {
        const int r = idx >> 7, c2 = idx & 127;
        *(unsigned int*)&Abuf[r * AST + 128 + c2 * 2] = 0u;
    }
    for (int idx = tid; idx < 16 * CST; idx += 1024) cbuf[idx] = 0.f;
    __syncthreads();

    // ---------------- encoder ----------------
    for (int t = 0; t < T_; ++t) {
        // stage x_t (fp32 -> bf16) into cols 0..127
        {
            const int r = tid >> 6, c2 = tid & 63;
            const float2 v = *(const float2*)(enc_in + (size_t)(m0 + r) * RS
                                              + (size_t)t * Dd + c2 * 2);
            const unsigned int u = ((unsigned int)f2b(v.y) << 16) | f2b(v.x);
            *(unsigned int*)&Abuf[r * AST + c2 * 2] = u;
        }
        __syncthreads();
        // layer0: z = [x|h2] @ Bp0 ; writes h1 -> cols 384..639
        z_mfma(Abuf, Bp0, 12, w, l, zw);
        lstm_epi(zw, b0p, cbuf, Abuf + 384, w, l);
        __syncthreads();
        // layer1: z = h1 @ (W1+U1) ; writes h2 -> cols 128..383
        z_mfma(Abuf + 384, Bp1, 8, w, l, zw);
        lstm_epi(zw, b1p, cbuf, Abuf + 128, w, l);
        __syncthreads();
    }

    // ---------------- decoder ----------------
    // stage inp0 = dec_in[:,0,:] into cols 0..127
    {
        const int r = tid >> 6, c2 = tid & 63;
        const float2 v = *(const float2*)(dec_in + (size_t)(m0 + r) * RS + c2 * 2);
        const unsigned int u = ((unsigned int)f2b(v.y) << 16) | f2b(v.x);
        *(unsigned int*)&Abuf[r * AST + c2 * 2] = u;
    }
    __syncthreads();

    for (int t = 0; t < T_; ++t) {
        if (t == 0) z_mfma(Abuf, Bd0, 12, w, l, zw);         // inp0@dW + h@dU
        else        z_mfma(Abuf + 128, Bpd, 8, w, l, zw);    // h@(dU + oW@dW)
        __syncthreads();   // all MFMA reads of h_d(t-1) done before overwrite
        lstm_epi(zw, (t == 0) ? bd0p : bDrp, cbuf, Abuf + 128, w, l);
        __syncthreads();   // h_d(t) visible
        // out(t) = h_d(t) @ oW + ob   (waves 0..7; overlaps next z_mfma)
        if (w < 8) {
            const int cn = l & 15, kg = l >> 4;
            const unsigned short* aptr = Abuf + cn * AST + 128 + kg * 8;
            const v8s* bp = BpO + (size_t)(w * 8) * 64 + l;
            v4f acc = {0.f, 0.f, 0.f, 0.f};
            #pragma unroll
            for (int kt = 0; kt < 8; ++kt) {
                const v8s a = *(const v8s*)(aptr + kt * 32);
                const v8s b = bp[kt * 64];
                acc = __builtin_amdgcn_mfma_f32_16x16x32_bf16(a, b, acc, 0, 0, 0);
            }
            const int d = w * 16 + cn;
            const float o4 = obp[d];
            #pragma unroll
            for (int reg = 0; reg < 4; ++reg) {
                const int r = kg * 4 + reg;
                out[(size_t)(m0 + r) * RS + (size_t)t * Dd + d] = acc[reg] + o4;
            }
        }
    }
}

extern "C" void kernel_launch(void* const* d_in, const int* in_sizes, int n_in,
                              void* d_out, int out_size, void* d_ws, size_t ws_size,
                              hipStream_t stream)
{
    const float* enc_in = (const float*)d_in[0];
    const float* dec_in = (const float*)d_in[1];
    const float* eW0 = (const float*)d_in[2];
    const float* eU0 = (const float*)d_in[3];
    const float* eb0 = (const float*)d_in[4];
    const float* eW1 = (const float*)d_in[5];
    const float* eU1 = (const float*)d_in[6];
    const float* eb1 = (const float*)d_in[7];
    const float* dW  = (const float*)d_in[8];
    const float* dU  = (const float*)d_in[9];
    const float* db  = (const float*)d_in[10];
    const float* oW  = (const float*)d_in[11];
    const float* ob  = (const float*)d_in[12];
    char* ws = (char*)d_ws;
    float* out = (float*)d_out;

    prep_kernel<<<5253, 256, 0, stream>>>(eW0, eU0, eb0, eW1, eU1, eb1,
                                          dW, dU, db, oW, ob, ws);
    lstm_main<<<32, 1024, 0, stream>>>(enc_in, dec_in, ws, out);
}